// Round 10
// baseline (300.536 us; speedup 1.0000x reference)
//
#include <hip/hip_runtime.h>

#define BATCH   1048576
#define IN_DIM  64
#define OUT_DIM 16
#define NBLOCKS 1024
#define NWAVES  (NBLOCKS * 4)          // 4096 waves, all resident (4 blocks/CU)
#define NTILES  (BATCH / 64)           // 16384 tiles of 64 rows
#define TPW     (NTILES / NWAVES)      // 4 tiles per wave

// ---------------------------------------------------------------------------
// Kernel 1: build At = A^T (64x16) -> ws[0:1024) and Ct = (G*A)^T (64x16)
// -> ws[1024:2048), where G = (A A^T)^-1. Gauss-Jordan w/ partial pivoting.
// Single block, 256 threads. (validated rounds 1-9)
// ---------------------------------------------------------------------------
__global__ __launch_bounds__(256) void precompute_kernel(
    const float* __restrict__ A, float* __restrict__ ws)
{
    __shared__ float sA[16][64];
    __shared__ float M[16][32];   // [S | I]
    __shared__ float fac[16];
    __shared__ int piv;

    const int tid = threadIdx.x;

    for (int i = tid; i < 1024; i += 256) sA[i >> 6][i & 63] = A[i];
    __syncthreads();

    {
        const int i = tid >> 4, j = tid & 15;
        float s = 0.f;
        #pragma unroll
        for (int k = 0; k < 64; ++k) s = fmaf(sA[i][k], sA[j][k], s);
        M[i][j] = s;
        M[i][16 + j] = (i == j) ? 1.f : 0.f;
    }
    __syncthreads();

    for (int p = 0; p < 16; ++p) {
        if (tid == 0) {
            int best = p;
            float bv = fabsf(M[p][p]);
            for (int r = p + 1; r < 16; ++r) {
                float v = fabsf(M[r][p]);
                if (v > bv) { bv = v; best = r; }
            }
            piv = best;
        }
        __syncthreads();
        if (tid < 32) {
            const int pr = piv;
            if (pr != p) { float t = M[p][tid]; M[p][tid] = M[pr][tid]; M[pr][tid] = t; }
        }
        __syncthreads();
        const float pv = M[p][p];
        __syncthreads();
        if (tid < 32) M[p][tid] *= (1.0f / pv);
        __syncthreads();
        if (tid < 16) fac[tid] = M[tid][p];
        __syncthreads();
        for (int e = tid; e < 512; e += 256) {
            const int r = e >> 5, c = e & 31;
            if (r != p) M[r][c] = fmaf(-fac[r], M[p][c], M[r][c]);
        }
        __syncthreads();
    }

    // At[k*16 + j] = A[j][k]
    for (int e = tid; e < 1024; e += 256) {
        const int k = e >> 4, j = e & 15;
        ws[e] = sA[j][k];
    }
    // Ct[k*16 + i] = C[i][k] = sum_j G[i][j] * A[j][k]
    for (int e = tid; e < 1024; e += 256) {
        const int k = e >> 4, i = e & 15;
        float s = 0.f;
        #pragma unroll
        for (int j = 0; j < 16; ++j) s = fmaf(M[i][16 + j], sA[j][k], s);
        ws[1024 + e] = s;
    }
}

// ---------------------------------------------------------------------------
// Kernel 2: x = y - C^T (A y - b), thread-per-row, cross-tile software
// pipeline. 4 resident blocks/CU, each wave owns 4 tiles of 64 rows. Per
// tile: k-half ping-pong through an 8 KB wave-private swizzled LDS buffer;
// the single staging set g[8] is refilled immediately after each consume, so
// ~8 KB of reads stays in flight during nearly all compute (duty-cycle fix
// for the measured 2.7 TB/s burst-idle ceiling). h0's y is captured to yr[8]
// during phase1a (32 regs, not R9's 64) so phase2a needs no re-read (R8 fix).
// Matrices ride the SMEM/K$ path. Wave-private buffer -> no barriers.
// ---------------------------------------------------------------------------
__global__ __launch_bounds__(256, 4) void apply_kernel(
    const float* __restrict__ y, const float* __restrict__ b,
    const float* __restrict__ ws, float* __restrict__ out)
{
    __shared__ float4 buf[4][64][8];   // 8 KB per wave

    const int tid  = threadIdx.x;
    const int wv   = tid >> 6;
    const int l    = tid & 63;
    const int srow = l >> 3;           // staging row-in-group 0..7
    const int ssl  = l & 7;            // staging 16B slot 0..7

    const float4* __restrict__ At4 = reinterpret_cast<const float4*>(ws);        // At[k][j]: k*4+jq
    const float4* __restrict__ Ct4 = reinterpret_cast<const float4*>(ws + 1024); // Ct[k][i]: k*4+iq

    // first tile for this wave; consecutive tiles are NWAVES apart
    const size_t tile0 = (size_t)blockIdx.x * 4 + wv;
    const float*  yb = y   + tile0 * 4096;                         // 64 rows * 64
    float*        ob = out + tile0 * 4096;
    const float4* bb = reinterpret_cast<const float4*>(b) + tile0 * 256;

    // ---- prologue: load h0(tile0) + b(tile0) ----
    float4 g[8];
    #pragma unroll
    for (int i = 0; i < 8; ++i)
        g[i] = *reinterpret_cast<const float4*>(yb + (i * 8 + srow) * 64 + ssl * 4);
    float4 bc[4];
    #pragma unroll
    for (int q = 0; q < 4; ++q) bc[q] = bb[l * 4 + q];

    for (int s = 0; s < TPW; ++s) {
        // ---- 1. commit h0 to LDS (vmcnt on g auto-inserted) ----
        #pragma unroll
        for (int i = 0; i < 8; ++i) {
            const int row = i * 8 + srow;
            buf[wv][row][ssl ^ (row & 7)] = g[i];
        }
        // ---- 2. issue h1 loads (in flight during phase1a) ----
        #pragma unroll
        for (int i = 0; i < 8; ++i)
            g[i] = *reinterpret_cast<const float4*>(yb + (i * 8 + srow) * 64 + 32 + ssl * 4);

        // ---- 3. t init + phase1a (k=0:32) + capture yr ----
        float t[16];
        t[ 0] = -bc[0].x; t[ 1] = -bc[0].y; t[ 2] = -bc[0].z; t[ 3] = -bc[0].w;
        t[ 4] = -bc[1].x; t[ 5] = -bc[1].y; t[ 6] = -bc[1].z; t[ 7] = -bc[1].w;
        t[ 8] = -bc[2].x; t[ 9] = -bc[2].y; t[10] = -bc[2].z; t[11] = -bc[2].w;
        t[12] = -bc[3].x; t[13] = -bc[3].y; t[14] = -bc[3].z; t[15] = -bc[3].w;

        float4 yr[8];
        #pragma unroll
        for (int q = 0; q < 8; ++q) {
            const float4 yv = buf[wv][l][q ^ (l & 7)];
            yr[q] = yv;
            #pragma unroll
            for (int dk = 0; dk < 4; ++dk) {
                const float yk = (dk == 0) ? yv.x : (dk == 1) ? yv.y :
                                 (dk == 2) ? yv.z : yv.w;
                const int k = q * 4 + dk;
                #pragma unroll
                for (int jq = 0; jq < 4; ++jq) {
                    const float4 a = At4[k * 4 + jq];
                    t[4*jq+0] = fmaf(a.x, yk, t[4*jq+0]);
                    t[4*jq+1] = fmaf(a.y, yk, t[4*jq+1]);
                    t[4*jq+2] = fmaf(a.z, yk, t[4*jq+2]);
                    t[4*jq+3] = fmaf(a.w, yk, t[4*jq+3]);
                }
            }
        }

        // ---- 4. commit h1 to LDS; prefetch next tile's h0 + b ----
        #pragma unroll
        for (int i = 0; i < 8; ++i) {
            const int row = i * 8 + srow;
            buf[wv][row][ssl ^ (row & 7)] = g[i];
        }
        if (s + 1 < TPW) {
            const float*  yn = yb + (size_t)NWAVES * 4096;
            const float4* bn = bb + (size_t)NWAVES * 256;
            #pragma unroll
            for (int i = 0; i < 8; ++i)
                g[i] = *reinterpret_cast<const float4*>(yn + (i * 8 + srow) * 64 + ssl * 4);
            #pragma unroll
            for (int q = 0; q < 4; ++q) bc[q] = bn[l * 4 + q];
        }

        // ---- 5. phase1b (k=32:64): t complete ----
        #pragma unroll
        for (int q = 0; q < 8; ++q) {
            const float4 yv = buf[wv][l][q ^ (l & 7)];
            #pragma unroll
            for (int dk = 0; dk < 4; ++dk) {
                const float yk = (dk == 0) ? yv.x : (dk == 1) ? yv.y :
                                 (dk == 2) ? yv.z : yv.w;
                const int k = 32 + q * 4 + dk;
                #pragma unroll
                for (int jq = 0; jq < 4; ++jq) {
                    const float4 a = At4[k * 4 + jq];
                    t[4*jq+0] = fmaf(a.x, yk, t[4*jq+0]);
                    t[4*jq+1] = fmaf(a.y, yk, t[4*jq+1]);
                    t[4*jq+2] = fmaf(a.z, yk, t[4*jq+2]);
                    t[4*jq+3] = fmaf(a.w, yk, t[4*jq+3]);
                }
            }
        }

        // ---- 6. phase2b: x[32:64] from LDS-resident y, in place ----
        #pragma unroll
        for (int q = 0; q < 8; ++q) {
            const float4 yv = buf[wv][l][q ^ (l & 7)];
            float xv[4];
            #pragma unroll
            for (int dk = 0; dk < 4; ++dk) {
                const int k = 32 + q * 4 + dk;
                float x = (dk == 0) ? yv.x : (dk == 1) ? yv.y :
                          (dk == 2) ? yv.z : yv.w;
                #pragma unroll
                for (int iq = 0; iq < 4; ++iq) {
                    const float4 c = Ct4[k * 4 + iq];
                    x = fmaf(-c.x, t[4*iq+0], x);
                    x = fmaf(-c.y, t[4*iq+1], x);
                    x = fmaf(-c.z, t[4*iq+2], x);
                    x = fmaf(-c.w, t[4*iq+3], x);
                }
                xv[dk] = x;
            }
            buf[wv][l][q ^ (l & 7)] = make_float4(xv[0], xv[1], xv[2], xv[3]);
        }
        // ---- 7. staged store h1 ----
        #pragma unroll
        for (int i = 0; i < 8; ++i) {
            const int row = i * 8 + srow;
            *reinterpret_cast<float4*>(ob + row * 64 + 32 + ssl * 4) =
                buf[wv][row][ssl ^ (row & 7)];
        }

        // ---- 8. phase2a: x[0:32] from yr (registers) ----
        #pragma unroll
        for (int q = 0; q < 8; ++q) {
            const float4 yv = yr[q];
            float xv[4];
            #pragma unroll
            for (int dk = 0; dk < 4; ++dk) {
                const int k = q * 4 + dk;
                float x = (dk == 0) ? yv.x : (dk == 1) ? yv.y :
                          (dk == 2) ? yv.z : yv.w;
                #pragma unroll
                for (int iq = 0; iq < 4; ++iq) {
                    const float4 c = Ct4[k * 4 + iq];
                    x = fmaf(-c.x, t[4*iq+0], x);
                    x = fmaf(-c.y, t[4*iq+1], x);
                    x = fmaf(-c.z, t[4*iq+2], x);
                    x = fmaf(-c.w, t[4*iq+3], x);
                }
                xv[dk] = x;
            }
            buf[wv][l][q ^ (l & 7)] = make_float4(xv[0], xv[1], xv[2], xv[3]);
        }
        // ---- 9. staged store h0 ----
        #pragma unroll
        for (int i = 0; i < 8; ++i) {
            const int row = i * 8 + srow;
            *reinterpret_cast<float4*>(ob + row * 64 + ssl * 4) =
                buf[wv][row][ssl ^ (row & 7)];
        }

        // ---- advance to this wave's next tile ----
        yb += (size_t)NWAVES * 4096;
        ob += (size_t)NWAVES * 4096;
        bb += (size_t)NWAVES * 256;
    }
}

// ---------------------------------------------------------------------------
extern "C" void kernel_launch(void* const* d_in, const int* in_sizes, int n_in,
                              void* d_out, int out_size, void* d_ws, size_t ws_size,
                              hipStream_t stream) {
    const float* y = (const float*)d_in[0];   // (1048576, 64)
    const float* A = (const float*)d_in[1];   // (16, 64)
    const float* b = (const float*)d_in[2];   // (1048576, 16)
    float* out = (float*)d_out;               // (1048576, 64)
    float* ws  = (float*)d_ws;                // 2048 floats: At(1024) + Ct(1024)

    precompute_kernel<<<1, 256, 0, stream>>>(A, ws);
    apply_kernel<<<NBLOCKS, 256, 0, stream>>>(y, b, ws, out);
}

// Round 11
// 165.033 us; speedup vs baseline: 1.8211x; 1.8211x over previous
//
#include <hip/hip_runtime.h>

#define BATCH   1048576
#define IN_DIM  64
#define OUT_DIM 16

// ---------------------------------------------------------------------------
// Kernel 1: build At = A^T (64x16) -> ws[0:1024) and Ct = (G*A)^T (64x16)
// -> ws[1024:2048), where G = (A A^T)^-1. Gauss-Jordan w/ partial pivoting.
// Single block, 256 threads. (validated rounds 1-10)
// ---------------------------------------------------------------------------
__global__ __launch_bounds__(256) void precompute_kernel(
    const float* __restrict__ A, float* __restrict__ ws)
{
    __shared__ float sA[16][64];
    __shared__ float M[16][32];   // [S | I]
    __shared__ float fac[16];
    __shared__ int piv;

    const int tid = threadIdx.x;

    for (int i = tid; i < 1024; i += 256) sA[i >> 6][i & 63] = A[i];
    __syncthreads();

    {
        const int i = tid >> 4, j = tid & 15;
        float s = 0.f;
        #pragma unroll
        for (int k = 0; k < 64; ++k) s = fmaf(sA[i][k], sA[j][k], s);
        M[i][j] = s;
        M[i][16 + j] = (i == j) ? 1.f : 0.f;
    }
    __syncthreads();

    for (int p = 0; p < 16; ++p) {
        if (tid == 0) {
            int best = p;
            float bv = fabsf(M[p][p]);
            for (int r = p + 1; r < 16; ++r) {
                float v = fabsf(M[r][p]);
                if (v > bv) { bv = v; best = r; }
            }
            piv = best;
        }
        __syncthreads();
        if (tid < 32) {
            const int pr = piv;
            if (pr != p) { float t = M[p][tid]; M[p][tid] = M[pr][tid]; M[pr][tid] = t; }
        }
        __syncthreads();
        const float pv = M[p][p];
        __syncthreads();
        if (tid < 32) M[p][tid] *= (1.0f / pv);
        __syncthreads();
        if (tid < 16) fac[tid] = M[tid][p];
        __syncthreads();
        for (int e = tid; e < 512; e += 256) {
            const int r = e >> 5, c = e & 31;
            if (r != p) M[r][c] = fmaf(-fac[r], M[p][c], M[r][c]);
        }
        __syncthreads();
    }

    // At[k*16 + j] = A[j][k]
    for (int e = tid; e < 1024; e += 256) {
        const int k = e >> 4, j = e & 15;
        ws[e] = sA[j][k];
    }
    // Ct[k*16 + i] = C[i][k] = sum_j G[i][j] * A[j][k]
    for (int e = tid; e < 1024; e += 256) {
        const int k = e >> 4, i = e & 15;
        float s = 0.f;
        #pragma unroll
        for (int j = 0; j < 16; ++j) s = fmaf(M[i][16 + j], sA[j][k], s);
        ws[1024 + e] = s;
    }
}

// ---------------------------------------------------------------------------
// Kernel 2: x = y - C^T (A y - b), thread-per-row, k-half ping-pong through
// an 8 KB/wave wave-private LDS buffer. All 20 VMEM loads (16 KB y + 64 B b)
// issue up-front; h0 is captured to yr[8] during phase1a so nothing is ever
// re-read. amdgpu_waves_per_eu(4,4) PINS 4 waves/SIMD: the compiler gets a
// 128-VGPR budget and cannot chase 8-wave occupancy by spilling (the R4/R9/
// R10 failure mode — VGPR=64 + hundreds of MB of scratch traffic). Peak live
// set ~90 regs by construction. Matrices ride the SMEM/K$ path; swizzle
// slot^(row&7) keeps LDS at the b128 floor. No barriers (wave-private).
// ---------------------------------------------------------------------------
__global__ __launch_bounds__(256)
__attribute__((amdgpu_waves_per_eu(4, 4)))
void apply_kernel(
    const float* __restrict__ y, const float* __restrict__ b,
    const float* __restrict__ ws, float* __restrict__ out)
{
    __shared__ float4 buf[4][64][8];   // 32 KB: 8 KB per wave, transient

    const int tid  = threadIdx.x;
    const int wv   = tid >> 6;
    const int l    = tid & 63;
    const int srow = l >> 3;           // staging row-in-group 0..7
    const int ssl  = l & 7;            // staging 16B slot 0..7

    const float4* __restrict__ At4 = reinterpret_cast<const float4*>(ws);        // At[k][j]: k*4+jq
    const float4* __restrict__ Ct4 = reinterpret_cast<const float4*>(ws + 1024); // Ct[k][i]: k*4+iq

    const size_t wbase = (size_t)blockIdx.x * 256 + (size_t)wv * 64;
    const float*  yb = y   + wbase * 64;
    float*        ob = out + wbase * 64;
    const float4* b4 = reinterpret_cast<const float4*>(b) + (wbase + l) * 4;

    // ---- issue ALL global loads up-front: ~17 KB/wave in flight ----
    float4 g0[8], g1[8];
    #pragma unroll
    for (int i = 0; i < 8; ++i)
        g0[i] = *reinterpret_cast<const float4*>(yb + (i * 8 + srow) * 64 + ssl * 4);
    #pragma unroll
    for (int i = 0; i < 8; ++i)
        g1[i] = *reinterpret_cast<const float4*>(yb + (i * 8 + srow) * 64 + 32 + ssl * 4);
    const float4 bv0 = b4[0], bv1 = b4[1], bv2 = b4[2], bv3 = b4[3];

    // ---- commit h0 to LDS (g0 dies here) ----
    #pragma unroll
    for (int i = 0; i < 8; ++i) {
        const int row = i * 8 + srow;
        buf[wv][row][ssl ^ (row & 7)] = g0[i];
    }

    // ---- t init from b ----
    float t[16];
    t[ 0] = -bv0.x; t[ 1] = -bv0.y; t[ 2] = -bv0.z; t[ 3] = -bv0.w;
    t[ 4] = -bv1.x; t[ 5] = -bv1.y; t[ 6] = -bv1.z; t[ 7] = -bv1.w;
    t[ 8] = -bv2.x; t[ 9] = -bv2.y; t[10] = -bv2.z; t[11] = -bv2.w;
    t[12] = -bv3.x; t[13] = -bv3.y; t[14] = -bv3.z; t[15] = -bv3.w;

    // ---- phase 1a (k=0:32): read row-wise from LDS, capture to yr ----
    float4 yr[8];
    #pragma unroll
    for (int q = 0; q < 8; ++q) {
        const float4 yv = buf[wv][l][q ^ (l & 7)];
        yr[q] = yv;
        #pragma unroll
        for (int dk = 0; dk < 4; ++dk) {
            const float yk = (dk == 0) ? yv.x : (dk == 1) ? yv.y :
                             (dk == 2) ? yv.z : yv.w;
            const int k = q * 4 + dk;
            #pragma unroll
            for (int jq = 0; jq < 4; ++jq) {
                const float4 a = At4[k * 4 + jq];
                t[4*jq+0] = fmaf(a.x, yk, t[4*jq+0]);
                t[4*jq+1] = fmaf(a.y, yk, t[4*jq+1]);
                t[4*jq+2] = fmaf(a.z, yk, t[4*jq+2]);
                t[4*jq+3] = fmaf(a.w, yk, t[4*jq+3]);
            }
        }
    }

    // ---- commit h1 to LDS (g1 dies here) ----
    #pragma unroll
    for (int i = 0; i < 8; ++i) {
        const int row = i * 8 + srow;
        buf[wv][row][ssl ^ (row & 7)] = g1[i];
    }

    // ---- phase 1b (k=32:64): t complete ----
    #pragma unroll
    for (int q = 0; q < 8; ++q) {
        const float4 yv = buf[wv][l][q ^ (l & 7)];
        #pragma unroll
        for (int dk = 0; dk < 4; ++dk) {
            const float yk = (dk == 0) ? yv.x : (dk == 1) ? yv.y :
                             (dk == 2) ? yv.z : yv.w;
            const int k = 32 + q * 4 + dk;
            #pragma unroll
            for (int jq = 0; jq < 4; ++jq) {
                const float4 a = At4[k * 4 + jq];
                t[4*jq+0] = fmaf(a.x, yk, t[4*jq+0]);
                t[4*jq+1] = fmaf(a.y, yk, t[4*jq+1]);
                t[4*jq+2] = fmaf(a.z, yk, t[4*jq+2]);
                t[4*jq+3] = fmaf(a.w, yk, t[4*jq+3]);
            }
        }
    }

    // ---- phase 2b: x[32:64] from LDS-resident y, written back in place ----
    #pragma unroll
    for (int q = 0; q < 8; ++q) {
        const float4 yv = buf[wv][l][q ^ (l & 7)];
        float xv[4];
        #pragma unroll
        for (int dk = 0; dk < 4; ++dk) {
            const int k = 32 + q * 4 + dk;
            float x = (dk == 0) ? yv.x : (dk == 1) ? yv.y :
                      (dk == 2) ? yv.z : yv.w;
            #pragma unroll
            for (int iq = 0; iq < 4; ++iq) {
                const float4 c = Ct4[k * 4 + iq];
                x = fmaf(-c.x, t[4*iq+0], x);
                x = fmaf(-c.y, t[4*iq+1], x);
                x = fmaf(-c.z, t[4*iq+2], x);
                x = fmaf(-c.w, t[4*iq+3], x);
            }
            xv[dk] = x;
        }
        buf[wv][l][q ^ (l & 7)] = make_float4(xv[0], xv[1], xv[2], xv[3]);
    }
    // ---- staged store h1 ----
    #pragma unroll
    for (int i = 0; i < 8; ++i) {
        const int row = i * 8 + srow;
        *reinterpret_cast<float4*>(ob + row * 64 + 32 + ssl * 4) =
            buf[wv][row][ssl ^ (row & 7)];
    }

    // ---- phase 2a: x[0:32] from yr (registers) ----
    #pragma unroll
    for (int q = 0; q < 8; ++q) {
        const float4 yv = yr[q];
        float xv[4];
        #pragma unroll
        for (int dk = 0; dk < 4; ++dk) {
            const int k = q * 4 + dk;
            float x = (dk == 0) ? yv.x : (dk == 1) ? yv.y :
                      (dk == 2) ? yv.z : yv.w;
            #pragma unroll
            for (int iq = 0; iq < 4; ++iq) {
                const float4 c = Ct4[k * 4 + iq];
                x = fmaf(-c.x, t[4*iq+0], x);
                x = fmaf(-c.y, t[4*iq+1], x);
                x = fmaf(-c.z, t[4*iq+2], x);
                x = fmaf(-c.w, t[4*iq+3], x);
            }
            xv[dk] = x;
        }
        buf[wv][l][q ^ (l & 7)] = make_float4(xv[0], xv[1], xv[2], xv[3]);
    }
    // ---- staged store h0 ----
    #pragma unroll
    for (int i = 0; i < 8; ++i) {
        const int row = i * 8 + srow;
        *reinterpret_cast<float4*>(ob + row * 64 + ssl * 4) =
            buf[wv][row][ssl ^ (row & 7)];
    }
}

// ---------------------------------------------------------------------------
extern "C" void kernel_launch(void* const* d_in, const int* in_sizes, int n_in,
                              void* d_out, int out_size, void* d_ws, size_t ws_size,
                              hipStream_t stream) {
    const float* y = (const float*)d_in[0];   // (1048576, 64)
    const float* A = (const float*)d_in[1];   // (16, 64)
    const float* b = (const float*)d_in[2];   // (1048576, 16)
    float* out = (float*)d_out;               // (1048576, 64)
    float* ws  = (float*)d_ws;                // 2048 floats: At(1024) + Ct(1024)

    precompute_kernel<<<1, 256, 0, stream>>>(A, ws);
    apply_kernel<<<BATCH / 256, 256, 0, stream>>>(y, b, ws, out);
}